// Round 1
// 1838.352 us; speedup vs baseline: 1.1873x; 1.1873x over previous
//
#include <hip/hip_runtime.h>

typedef unsigned short u16;
typedef short short8 __attribute__((ext_vector_type(8)));
typedef float f32x4 __attribute__((ext_vector_type(4)));

struct __attribute__((aligned(8), may_alias)) U2 { unsigned int x, y; };
struct __attribute__((aligned(16), may_alias)) U4 { unsigned int x, y, z, w; };
struct __attribute__((aligned(16), may_alias)) F4 { float x, y, z, w; };

__device__ __forceinline__ float bf2f(u16 h) {
    union { unsigned int u; float f; } x; x.u = ((unsigned int)h) << 16; return x.f;
}
__device__ __forceinline__ u16 f2bf(float f) {
    union { float f; unsigned int u; } x; x.f = f;
    return (u16)((x.u + 0x7FFFu + ((x.u >> 16) & 1u)) >> 16);
}
__device__ __forceinline__ short8 lds8(const u16* p) {
    union { U2 q[2]; short8 s; } u;
    u.q[0] = *(const U2*)p;
    u.q[1] = *(const U2*)(p + 4);
    return u.s;
}
// async global->LDS, 16B per lane; LDS dest must be linear (base + lane*16)
__device__ __forceinline__ void gl_lds16(const u16* g, u16* l) {
    __builtin_amdgcn_global_load_lds(
        (const __attribute__((address_space(1))) void*)g,
        (__attribute__((address_space(3))) void*)l, 16, 0, 0);
}

// ---------------------------------------------------------------------------
// Transpose 5 fp32 weight matrices (2048x2048) into bf16: Wt[n][k] = bf16(W[k][n])
// ---------------------------------------------------------------------------
__global__ void transpose5(const float* __restrict__ s0, const float* __restrict__ s1,
                           const float* __restrict__ s2, const float* __restrict__ s3,
                           const float* __restrict__ s4,
                           u16* __restrict__ d0, u16* __restrict__ d1,
                           u16* __restrict__ d2, u16* __restrict__ d3,
                           u16* __restrict__ d4)
{
    const float* S; u16* D;
    switch (blockIdx.z) {
        case 0: S = s0; D = d0; break;
        case 1: S = s1; D = d1; break;
        case 2: S = s2; D = d2; break;
        case 3: S = s3; D = d3; break;
        default: S = s4; D = d4; break;
    }
    __shared__ float tile[32][33];
    int tx = threadIdx.x, ty = threadIdx.y;
    int bx = blockIdx.x * 32, by = blockIdx.y * 32;
    #pragma unroll
    for (int i = 0; i < 32; i += 8)
        tile[ty + i][tx] = S[(size_t)(by + ty + i) * 2048 + bx + tx];
    __syncthreads();
    #pragma unroll
    for (int i = 0; i < 32; i += 8)
        D[(size_t)(bx + ty + i) * 2048 + by + tx] = f2bf(tile[tx][ty + i]);
}

// ---------------------------------------------------------------------------
// Token-shift mix -> bf16:  out[t][c] = bf16(xprev[c] + tmix[c]*(x[t][c]-xprev[c]))
// xprev = 0 at t % 4096 == 0. One block per row; 256 thr x 8 cols.
// ---------------------------------------------------------------------------
__global__ __launch_bounds__(256, 4) void mix_rows(
    const float* __restrict__ x, const float* __restrict__ tmix, u16* __restrict__ out)
{
    const int t = blockIdx.x;
    const int c = threadIdx.x * 8;
    const float* xp = x + (size_t)t * 2048 + c;
    const bool first = (t & 4095) == 0;
    F4 a0 = *(const F4*)xp, a1 = *(const F4*)(xp + 4);
    F4 p0 = {0.f, 0.f, 0.f, 0.f}, p1 = {0.f, 0.f, 0.f, 0.f};
    if (!first) { p0 = *(const F4*)(xp - 2048); p1 = *(const F4*)(xp - 2048 + 4); }
    F4 t0 = *(const F4*)(tmix + c), t1 = *(const F4*)(tmix + c + 4);
    float xc[8] = {a0.x, a0.y, a0.z, a0.w, a1.x, a1.y, a1.z, a1.w};
    float xq[8] = {p0.x, p0.y, p0.z, p0.w, p1.x, p1.y, p1.z, p1.w};
    float tm[8] = {t0.x, t0.y, t0.z, t0.w, t1.x, t1.y, t1.z, t1.w};
    union { u16 s[8]; U4 v; } ov;
    #pragma unroll
    for (int e = 0; e < 8; ++e)
        ov.s[e] = f2bf(xq[e] + tm[e] * (xc[e] - xq[e]));
    *(U4*)(out + (size_t)t * 2048 + c) = ov.v;
}

// ---------------------------------------------------------------------------
// m97-structure GEMM: C[M,N] = A_bf16[M,K] @ Bt_bf16[N,K]^T, fp32 accum.
// 128x128 tile, BK=32, 4 waves, 4x4 16x16x32 frags/wave,
// global_load_lds width-16 staging into LINEAR LDS, 2 barriers per K-step.
// ---------------------------------------------------------------------------
__device__ __forceinline__ void storeC(u16* p, float v) { *p = f2bf(v); }
__device__ __forceinline__ void storeC(float* p, float v) { *p = v; }

template <typename CT>
__global__ __launch_bounds__(256, 1) void gemm_bt(
    const u16* __restrict__ A, const u16* __restrict__ Bt, CT* __restrict__ C,
    int M, int N, int K)
{
    __shared__ u16 As[128][32];
    __shared__ u16 Bs[128][32];
    const int tid = threadIdx.x;
    const int lane = tid & 63, wv = tid >> 6;
    const int quad = lane >> 4, l16 = lane & 15;
    const int wm = (wv >> 1) * 64, wn = (wv & 1) * 64;
    const int bm = blockIdx.x * 128, bn = blockIdx.y * 128;

    // staging coords: element e = it*256 + tid covers 16B; row = e>>2, seg = e&3.
    // within a wave the LDS byte offset is base + lane*16 (linear) as required.
    const int sr = tid >> 2, ss = tid & 3;
    const u16* ga0 = A + (size_t)(bm + sr) * K + ss * 8;
    const u16* ga1 = A + (size_t)(bm + sr + 64) * K + ss * 8;
    const u16* gb0 = Bt + (size_t)(bn + sr) * K + ss * 8;
    const u16* gb1 = Bt + (size_t)(bn + sr + 64) * K + ss * 8;
    u16* la0 = &As[sr][ss * 8];
    u16* la1 = &As[sr + 64][ss * 8];
    u16* lb0 = &Bs[sr][ss * 8];
    u16* lb1 = &Bs[sr + 64][ss * 8];

    f32x4 acc[4][4];
    const f32x4 zero4 = {0.f, 0.f, 0.f, 0.f};
    #pragma unroll
    for (int i = 0; i < 4; ++i)
        #pragma unroll
        for (int j = 0; j < 4; ++j) acc[i][j] = zero4;

    for (int k0 = 0; k0 < K; k0 += 32) {
        __syncthreads();                    // prior ds_reads done -> safe to overwrite
        gl_lds16(ga0 + k0, la0);
        gl_lds16(ga1 + k0, la1);
        gl_lds16(gb0 + k0, lb0);
        gl_lds16(gb1 + k0, lb1);
        __syncthreads();                    // drains vmcnt(0): tile visible
        short8 af[4], bfv[4];
        #pragma unroll
        for (int mt = 0; mt < 4; ++mt) af[mt] = lds8(&As[wm + mt * 16 + l16][quad * 8]);
        #pragma unroll
        for (int nt = 0; nt < 4; ++nt) bfv[nt] = lds8(&Bs[wn + nt * 16 + l16][quad * 8]);
        #pragma unroll
        for (int mt = 0; mt < 4; ++mt)
            #pragma unroll
            for (int nt = 0; nt < 4; ++nt)
                acc[mt][nt] = __builtin_amdgcn_mfma_f32_16x16x32_bf16(
                    af[mt], bfv[nt], acc[mt][nt], 0, 0, 0);
    }
    #pragma unroll
    for (int mt = 0; mt < 4; ++mt)
        #pragma unroll
        for (int nt = 0; nt < 4; ++nt)
            #pragma unroll
            for (int r = 0; r < 4; ++r) {
                int row = bm + wm + mt * 16 + quad * 4 + r;
                int col = bn + wn + nt * 16 + l16;
                storeC(&C[(size_t)row * N + col], acc[mt][nt][r]);
            }
}

// ---------------------------------------------------------------------------
// WKV chunked scan + fused groupnorm/silu-gate epilogue. (unchanged this round)
// ---------------------------------------------------------------------------
__global__ __launch_bounds__(512, 1) void wkv_kernel(
    const u16* __restrict__ Rb, const u16* __restrict__ Kb,
    const u16* __restrict__ Vb, const u16* __restrict__ Gb,
    const float* __restrict__ td, const float* __restrict__ tf,
    const float* __restrict__ gamma, const float* __restrict__ beta,
    const float* __restrict__ st0, u16* __restrict__ Xout)
{
    __shared__ u16 kt[64][72];     // k tile [t_local][s]
    __shared__ u16 vtT[64][72];    // v tile transposed [s][t_local]
    __shared__ u16 Pb[8][64][40];  // per-wave P scratch (32-col halves); also aliases stT
    __shared__ float wpow[513];    // w1^p
    u16* stT = &Pb[0][0][0];       // [64][72] view: stT[s2*72 + s1] = state[s1][s2]

    const int blk = blockIdx.x;
    const int b = blk >> 5, h = blk & 31;
    const int tid = threadIdx.x;
    const int w = tid >> 6, lane = tid & 63;
    const int quad = lane >> 4, l16 = lane & 15;

    const float E = expf(td[h]);   // ln(1/w1)
    const float u = tf[h];
    for (int p = tid; p <= 512; p += 512) wpow[p] = expf(-(float)p * E);

    // state registers
    const int mtS = w >> 1;
    const int ntS0 = (w & 1) * 2;
    f32x4 stReg[2];
    {
        const float* sp = st0 + (((size_t)b * 32 + h) << 12);
        #pragma unroll
        for (int q = 0; q < 2; ++q)
            #pragma unroll
            for (int r = 0; r < 4; ++r) {
                int s1 = mtS * 16 + quad * 4 + r;
                int s2 = (ntS0 + q) * 16 + l16;
                stReg[q][r] = sp[s1 * 64 + s2];
            }
    }

    const size_t rowbase = ((size_t)b * 4096) * 2048 + (size_t)h * 64;
    const f32x4 zero4 = {0.f, 0.f, 0.f, 0.f};
    __syncthreads();  // wpow ready

    for (int c = 0; c < 8; ++c) {
        const int t0 = c * 512;
        __syncthreads();  // guard Pb/kt/vtT reuse from prior chunk
        // ---- broadcast state to LDS (bf16, transposed) ----
        #pragma unroll
        for (int q = 0; q < 2; ++q)
            #pragma unroll
            for (int r = 0; r < 4; ++r) {
                int s1 = mtS * 16 + quad * 4 + r;
                int s2 = (ntS0 + q) * 16 + l16;
                stT[s2 * 72 + s1] = f2bf(stReg[q][r]);
            }
        __syncthreads();

        // ---- load r fragments for this wave's 64 rows ----
        short8 ar[4][2];
        #pragma unroll
        for (int mt = 0; mt < 4; ++mt)
            #pragma unroll
            for (int ks = 0; ks < 2; ++ks) {
                int t = t0 + w * 64 + mt * 16 + l16;
                const u16* p = Rb + rowbase + (size_t)t * 2048 + ks * 32 + quad * 8;
                union { U4 v; short8 s; } uu; uu.v = *(const U4*)p;
                ar[mt][ks] = uu.s;
            }

        // ---- phase 1: acc = (r @ state) * w1^i ----
        f32x4 acc[4][4];
        #pragma unroll
        for (int i = 0; i < 4; ++i)
            #pragma unroll
            for (int j = 0; j < 4; ++j) acc[i][j] = zero4;
        #pragma unroll
        for (int ks = 0; ks < 2; ++ks)
            #pragma unroll
            for (int nt = 0; nt < 4; ++nt) {
                short8 bs = lds8(&stT[(nt * 16 + l16) * 72 + ks * 32 + quad * 8]);
                #pragma unroll
                for (int mt = 0; mt < 4; ++mt)
                    acc[mt][nt] = __builtin_amdgcn_mfma_f32_16x16x32_bf16(
                        ar[mt][ks], bs, acc[mt][nt], 0, 0, 0);
            }
        #pragma unroll
        for (int mt = 0; mt < 4; ++mt)
            #pragma unroll
            for (int r = 0; r < 4; ++r) {
                float f = wpow[w * 64 + mt * 16 + quad * 4 + r];
                #pragma unroll
                for (int nt = 0; nt < 4; ++nt) acc[mt][nt][r] *= f;
            }

        f32x4 sacc[2] = {zero4, zero4};

        // ---- phase 2: J-tile loop (attention + state partials) ----
        for (int J = 0; J < 8; ++J) {
            __syncthreads();
            {   // stage kt, vtT
                int row = tid >> 3, seg = tid & 7;
                size_t goff = rowbase + (size_t)(t0 + J * 64 + row) * 2048 + seg * 8;
                union { U4 v; u16 s[8]; } kv, vv;
                kv.v = *(const U4*)(Kb + goff);
                vv.v = *(const U4*)(Vb + goff);
                *(U4*)&kt[row][seg * 8] = kv.v;
                #pragma unroll
                for (int e = 0; e < 8; ++e) vtT[seg * 8 + e][row] = vv.s[e];
            }
            __syncthreads();
            if (w >= J) {
                #pragma unroll
                for (int half = 0; half < 2; ++half) {
                    #pragma unroll
                    for (int jt2 = 0; jt2 < 2; ++jt2) {
                        int jt = half * 2 + jt2;
                        short8 bk0 = lds8(&kt[jt * 16 + l16][quad * 8]);
                        short8 bk1 = lds8(&kt[jt * 16 + l16][32 + quad * 8]);
                        #pragma unroll
                        for (int mt = 0; mt < 4; ++mt) {
                            f32x4 s4 = zero4;
                            s4 = __builtin_amdgcn_mfma_f32_16x16x32_bf16(ar[mt][0], bk0, s4, 0, 0, 0);
                            s4 = __builtin_amdgcn_mfma_f32_16x16x32_bf16(ar[mt][1], bk1, s4, 0, 0, 0);
                            int ibase = w * 64 + mt * 16 + quad * 4;
                            int j = J * 64 + jt * 16 + l16;
                            #pragma unroll
                            for (int r = 0; r < 4; ++r) {
                                int i = ibase + r;
                                float f = (j < i) ? wpow[i - j - 1] : ((j == i) ? u : 0.f);
                                Pb[w][mt * 16 + quad * 4 + r][jt2 * 16 + l16] = f2bf(s4[r] * f);
                            }
                        }
                    }
                    __builtin_amdgcn_wave_barrier();
                    short8 ap[4];
                    #pragma unroll
                    for (int mt = 0; mt < 4; ++mt)
                        ap[mt] = lds8(&Pb[w][mt * 16 + l16][quad * 8]);
                    #pragma unroll
                    for (int nt = 0; nt < 4; ++nt) {
                        short8 bv = lds8(&vtT[nt * 16 + l16][half * 32 + quad * 8]);
                        #pragma unroll
                        for (int mt = 0; mt < 4; ++mt)
                            acc[mt][nt] = __builtin_amdgcn_mfma_f32_16x16x32_bf16(
                                ap[mt], bv, acc[mt][nt], 0, 0, 0);
                    }
                }
            }
            // state partial: s_part += (k * w1^(511-t))^T @ v  for this J tile
            {
                short8 aS[2];
                #pragma unroll
                for (int ks = 0; ks < 2; ++ks) {
                    union { short8 s; u16 us[8]; } t8;
                    #pragma unroll
                    for (int jj = 0; jj < 8; ++jj) {
                        int tl = ks * 32 + quad * 8 + jj;
                        float f = bf2f(kt[tl][mtS * 16 + l16]) * wpow[511 - (J * 64 + tl)];
                        t8.us[jj] = f2bf(f);
                    }
                    aS[ks] = t8.s;
                }
                #pragma unroll
                for (int q = 0; q < 2; ++q) {
                    short8 bv0 = lds8(&vtT[(ntS0 + q) * 16 + l16][quad * 8]);
                    short8 bv1 = lds8(&vtT[(ntS0 + q) * 16 + l16][32 + quad * 8]);
                    sacc[q] = __builtin_amdgcn_mfma_f32_16x16x32_bf16(aS[0], bv0, sacc[q], 0, 0, 0);
                    sacc[q] = __builtin_amdgcn_mfma_f32_16x16x32_bf16(aS[1], bv1, sacc[q], 0, 0, 0);
                }
            }
        }

        // ---- state update (registers only) ----
        {
            float wsT = wpow[512];
            #pragma unroll
            for (int q = 0; q < 2; ++q)
                #pragma unroll
                for (int r = 0; r < 4; ++r)
                    stReg[q][r] = wsT * stReg[q][r] + sacc[q][r];
        }

        // ---- epilogue: groupnorm(out/8)*gamma+beta, * silu(g), write bf16 ----
        #pragma unroll
        for (int mt = 0; mt < 4; ++mt) {
            float rsum[4], rsq[4];
            #pragma unroll
            for (int r = 0; r < 4; ++r) {
                float s = 0.f, sq = 0.f;
                #pragma unroll
                for (int nt = 0; nt < 4; ++nt) {
                    float v = acc[mt][nt][r];
                    s += v; sq += v * v;
                }
                rsum[r] = s; rsq[r] = sq;
            }
            #pragma unroll
            for (int off = 1; off < 16; off <<= 1)
                #pragma unroll
                for (int r = 0; r < 4; ++r) {
                    rsum[r] += __shfl_xor(rsum[r], off);
                    rsq[r] += __shfl_xor(rsq[r], off);
                }
            #pragma unroll
            for (int r = 0; r < 4; ++r) {
                float mean = rsum[r] * (1.f / 512.f);   // mean of acc/8 over 64 ch
                float var = rsq[r] * (1.f / 4096.f) - mean * mean;
                float rstd = rsqrtf(var + 1e-5f);
                int tg = t0 + w * 64 + mt * 16 + quad * 4 + r;
                size_t obase = rowbase + (size_t)tg * 2048;
                #pragma unroll
                for (int nt = 0; nt < 4; ++nt) {
                    int ch = nt * 16 + l16;
                    float y = acc[mt][nt][r] * 0.125f;
                    float xn = (y - mean) * rstd * gamma[h * 64 + ch] + beta[h * 64 + ch];
                    float gl = bf2f(Gb[obase + ch]);
                    float sg = gl / (1.f + expf(-gl));
                    Xout[obase + ch] = f2bf(xn * sg);
                }
            }
        }
    }
}

// ---------------------------------------------------------------------------
extern "C" void kernel_launch(void* const* d_in, const int* in_sizes, int n_in,
                              void* d_out, int out_size, void* d_ws, size_t ws_size,
                              hipStream_t stream)
{
    const float* x   = (const float*)d_in[0];
    const float* Wr  = (const float*)d_in[1];
    const float* Wk  = (const float*)d_in[2];
    const float* Wv  = (const float*)d_in[3];
    const float* Wg  = (const float*)d_in[4];
    const float* Wo  = (const float*)d_in[5];
    const float* gam = (const float*)d_in[6];
    const float* bet = (const float*)d_in[7];
    const float* tmk = (const float*)d_in[8];
    const float* tmv = (const float*)d_in[9];
    const float* tmr = (const float*)d_in[10];
    const float* tmg = (const float*)d_in[11];
    const float* td  = (const float*)d_in[12];
    const float* tf  = (const float*)d_in[13];
    const float* st0 = (const float*)d_in[14];
    float* out = (float*)d_out;

    char* ws = (char*)d_ws;
    const size_t WSZ = (size_t)2048 * 2048 * 2;   // 8 MiB per transposed bf16 weight
    const size_t ASZ = (size_t)16384 * 2048 * 2;  // 64 MiB per bf16 activation
    u16* WtR = (u16*)(ws + 0 * WSZ);
    u16* WtK = (u16*)(ws + 1 * WSZ);
    u16* WtV = (u16*)(ws + 2 * WSZ);
    u16* WtG = (u16*)(ws + 3 * WSZ);
    u16* WtO = (u16*)(ws + 4 * WSZ);
    char* act = ws + 5 * WSZ;
    u16* rb = (u16*)(act + 0 * ASZ);
    u16* kb = (u16*)(act + 1 * ASZ);
    u16* vb = (u16*)(act + 2 * ASZ);
    u16* gb = (u16*)(act + 3 * ASZ);
    u16* xo = gb;  // alias: wkv epilogue reads Gb[addr] strictly before writing Xout[addr]

    // scratch for the mixed bf16 A: first 64 MiB of the fp32 output buffer.
    // It is fully consumed before wkv runs; gemm_bt<float> overwrites it at the end.
    u16* mixA = (u16*)d_out;

    transpose5<<<dim3(64, 64, 5), dim3(32, 8), 0, stream>>>(
        Wr, Wk, Wv, Wg, Wo, WtR, WtK, WtV, WtG, WtO);

    dim3 ggrid(128, 16), gblk(256);
    dim3 mgrid(16384), mblk(256);

    mix_rows<<<mgrid, mblk, 0, stream>>>(x, tmr, mixA);
    gemm_bt<u16><<<ggrid, gblk, 0, stream>>>(mixA, WtR, rb, 16384, 2048, 2048);
    mix_rows<<<mgrid, mblk, 0, stream>>>(x, tmk, mixA);
    gemm_bt<u16><<<ggrid, gblk, 0, stream>>>(mixA, WtK, kb, 16384, 2048, 2048);
    mix_rows<<<mgrid, mblk, 0, stream>>>(x, tmv, mixA);
    gemm_bt<u16><<<ggrid, gblk, 0, stream>>>(mixA, WtV, vb, 16384, 2048, 2048);
    mix_rows<<<mgrid, mblk, 0, stream>>>(x, tmg, mixA);
    gemm_bt<u16><<<ggrid, gblk, 0, stream>>>(mixA, WtG, gb, 16384, 2048, 2048);

    wkv_kernel<<<dim3(128), dim3(512), 0, stream>>>(
        rb, kb, vb, gb, td, tf, gam, bet, st0, xo);

    gemm_bt<float><<<ggrid, gblk, 0, stream>>>(xo, WtO, out, 16384, 2048, 2048);
}

// Round 3
// 1607.750 us; speedup vs baseline: 1.3576x; 1.1434x over previous
//
#include <hip/hip_runtime.h>

typedef unsigned short u16;
typedef short short8 __attribute__((ext_vector_type(8)));
typedef float f32x4 __attribute__((ext_vector_type(4)));

struct __attribute__((aligned(8), may_alias)) U2 { unsigned int x, y; };
struct __attribute__((aligned(16), may_alias)) U4 { unsigned int x, y, z, w; };
struct __attribute__((aligned(16), may_alias)) F4 { float x, y, z, w; };

__device__ __forceinline__ float bf2f(u16 h) {
    union { unsigned int u; float f; } x; x.u = ((unsigned int)h) << 16; return x.f;
}
__device__ __forceinline__ u16 f2bf(float f) {
    union { float f; unsigned int u; } x; x.f = f;
    return (u16)((x.u + 0x7FFFu + ((x.u >> 16) & 1u)) >> 16);
}
__device__ __forceinline__ short8 lds8(const u16* p) {
    union { U2 q[2]; short8 s; } u;
    u.q[0] = *(const U2*)p;
    u.q[1] = *(const U2*)(p + 4);
    return u.s;
}
// async global->LDS, 16B per lane; LDS dest must be linear (base + lane*16)
__device__ __forceinline__ void gl_lds16(const u16* g, u16* l) {
    __builtin_amdgcn_global_load_lds(
        (const __attribute__((address_space(1))) void*)g,
        (__attribute__((address_space(3))) void*)l, 16, 0, 0);
}

// ---------------------------------------------------------------------------
// Transpose 5 fp32 weight matrices (2048x2048) into bf16: Wt[n][k] = bf16(W[k][n])
// ---------------------------------------------------------------------------
__global__ void transpose5(const float* __restrict__ s0, const float* __restrict__ s1,
                           const float* __restrict__ s2, const float* __restrict__ s3,
                           const float* __restrict__ s4,
                           u16* __restrict__ d0, u16* __restrict__ d1,
                           u16* __restrict__ d2, u16* __restrict__ d3,
                           u16* __restrict__ d4)
{
    const float* S; u16* D;
    switch (blockIdx.z) {
        case 0: S = s0; D = d0; break;
        case 1: S = s1; D = d1; break;
        case 2: S = s2; D = d2; break;
        case 3: S = s3; D = d3; break;
        default: S = s4; D = d4; break;
    }
    __shared__ float tile[32][33];
    int tx = threadIdx.x, ty = threadIdx.y;
    int bx = blockIdx.x * 32, by = blockIdx.y * 32;
    #pragma unroll
    for (int i = 0; i < 32; i += 8)
        tile[ty + i][tx] = S[(size_t)(by + ty + i) * 2048 + bx + tx];
    __syncthreads();
    #pragma unroll
    for (int i = 0; i < 32; i += 8)
        D[(size_t)(bx + ty + i) * 2048 + by + tx] = f2bf(tile[tx][ty + i]);
}

// ---------------------------------------------------------------------------
// Token-shift mix -> bf16, two params at once (halves x re-reads):
//   out[t][c] = bf16(xprev[c] + tmix[c]*(x[t][c]-xprev[c])), xprev=0 at t%4096==0
// ---------------------------------------------------------------------------
__global__ __launch_bounds__(256, 4) void mix2_rows(
    const float* __restrict__ x, const float* __restrict__ tmA,
    const float* __restrict__ tmB, u16* __restrict__ outA, u16* __restrict__ outB)
{
    const int t = blockIdx.x;
    const int c = threadIdx.x * 8;
    const float* xp = x + (size_t)t * 2048 + c;
    const bool first = (t & 4095) == 0;
    F4 a0 = *(const F4*)xp, a1 = *(const F4*)(xp + 4);
    F4 p0 = {0.f, 0.f, 0.f, 0.f}, p1 = {0.f, 0.f, 0.f, 0.f};
    if (!first) { p0 = *(const F4*)(xp - 2048); p1 = *(const F4*)(xp - 2048 + 4); }
    F4 ta0 = *(const F4*)(tmA + c), ta1 = *(const F4*)(tmA + c + 4);
    F4 tb0 = *(const F4*)(tmB + c), tb1 = *(const F4*)(tmB + c + 4);
    float xc[8] = {a0.x, a0.y, a0.z, a0.w, a1.x, a1.y, a1.z, a1.w};
    float xq[8] = {p0.x, p0.y, p0.z, p0.w, p1.x, p1.y, p1.z, p1.w};
    float ma[8] = {ta0.x, ta0.y, ta0.z, ta0.w, ta1.x, ta1.y, ta1.z, ta1.w};
    float mb[8] = {tb0.x, tb0.y, tb0.z, tb0.w, tb1.x, tb1.y, tb1.z, tb1.w};
    union { u16 s[8]; U4 v; } oa, ob;
    #pragma unroll
    for (int e = 0; e < 8; ++e) {
        float d = xc[e] - xq[e];
        oa.s[e] = f2bf(xq[e] + ma[e] * d);
        ob.s[e] = f2bf(xq[e] + mb[e] * d);
    }
    *(U4*)(outA + (size_t)t * 2048 + c) = oa.v;
    *(U4*)(outB + (size_t)t * 2048 + c) = ob.v;
}

// ---------------------------------------------------------------------------
// m97-structure GEMM: C[M,N] = A_bf16[M,K] @ Bt_bf16[N,K]^T, fp32 accum.
// ---------------------------------------------------------------------------
__device__ __forceinline__ void storeC(u16* p, float v) { *p = f2bf(v); }
__device__ __forceinline__ void storeC(float* p, float v) { *p = v; }

template <typename CT>
__global__ __launch_bounds__(256, 1) void gemm_bt(
    const u16* __restrict__ A, const u16* __restrict__ Bt, CT* __restrict__ C,
    int M, int N, int K)
{
    __shared__ u16 As[128][32];
    __shared__ u16 Bs[128][32];
    const int tid = threadIdx.x;
    const int lane = tid & 63, wv = tid >> 6;
    const int quad = lane >> 4, l16 = lane & 15;
    const int wm = (wv >> 1) * 64, wn = (wv & 1) * 64;
    const int bm = blockIdx.x * 128, bn = blockIdx.y * 128;

    const int sr = tid >> 2, ss = tid & 3;
    const u16* ga0 = A + (size_t)(bm + sr) * K + ss * 8;
    const u16* ga1 = A + (size_t)(bm + sr + 64) * K + ss * 8;
    const u16* gb0 = Bt + (size_t)(bn + sr) * K + ss * 8;
    const u16* gb1 = Bt + (size_t)(bn + sr + 64) * K + ss * 8;
    u16* la0 = &As[sr][ss * 8];
    u16* la1 = &As[sr + 64][ss * 8];
    u16* lb0 = &Bs[sr][ss * 8];
    u16* lb1 = &Bs[sr + 64][ss * 8];

    f32x4 acc[4][4];
    const f32x4 zero4 = {0.f, 0.f, 0.f, 0.f};
    #pragma unroll
    for (int i = 0; i < 4; ++i)
        #pragma unroll
        for (int j = 0; j < 4; ++j) acc[i][j] = zero4;

    for (int k0 = 0; k0 < K; k0 += 32) {
        __syncthreads();
        gl_lds16(ga0 + k0, la0);
        gl_lds16(ga1 + k0, la1);
        gl_lds16(gb0 + k0, lb0);
        gl_lds16(gb1 + k0, lb1);
        __syncthreads();
        short8 af[4], bfv[4];
        #pragma unroll
        for (int mt = 0; mt < 4; ++mt) af[mt] = lds8(&As[wm + mt * 16 + l16][quad * 8]);
        #pragma unroll
        for (int nt = 0; nt < 4; ++nt) bfv[nt] = lds8(&Bs[wn + nt * 16 + l16][quad * 8]);
        #pragma unroll
        for (int mt = 0; mt < 4; ++mt)
            #pragma unroll
            for (int nt = 0; nt < 4; ++nt)
                acc[mt][nt] = __builtin_amdgcn_mfma_f32_16x16x32_bf16(
                    af[mt], bfv[nt], acc[mt][nt], 0, 0, 0);
    }
    #pragma unroll
    for (int mt = 0; mt < 4; ++mt)
        #pragma unroll
        for (int nt = 0; nt < 4; ++nt)
            #pragma unroll
            for (int r = 0; r < 4; ++r) {
                int row = bm + wm + mt * 16 + quad * 4 + r;
                int col = bn + wn + nt * 16 + l16;
                storeC(&C[(size_t)row * N + col], acc[mt][nt][r]);
            }
}

// ---------------------------------------------------------------------------
// WKV pass A: per-(b,h,chunk) state contribution
//   Sc[s1][s2] = sum_t k[t][s1] * w1^(511-t) * v[t][s2]   (t chunk-local)
// Grid 1024 blocks (b*256 + h*8 + c), 256 threads (4 waves).
// ---------------------------------------------------------------------------
__global__ __launch_bounds__(256, 2) void wkv_state(
    const u16* __restrict__ Kb, const u16* __restrict__ Vb,
    const float* __restrict__ td, float* __restrict__ Sc)
{
    __shared__ u16 ktT[64][72];   // [s][t_local]  pre-scaled by w1^(511-t)
    __shared__ u16 vtT[64][72];   // [s][t_local]
    __shared__ float wpow[512];

    const int blk = blockIdx.x;
    const int c = blk & 7, h = (blk >> 3) & 31, b = blk >> 8;
    const int tid = threadIdx.x;
    const int w = tid >> 6, lane = tid & 63;
    const int quad = lane >> 4, l16 = lane & 15;

    const float E = expf(td[h]);
    for (int p = tid; p < 512; p += 256) wpow[p] = expf(-(float)p * E);

    const size_t rowbase = ((size_t)b * 4096 + c * 512) * 2048 + (size_t)h * 64;
    const f32x4 zero4 = {0.f, 0.f, 0.f, 0.f};
    f32x4 acc[4];
    #pragma unroll
    for (int nt = 0; nt < 4; ++nt) acc[nt] = zero4;
    __syncthreads();  // wpow ready

    for (int J = 0; J < 8; ++J) {
        __syncthreads();
        #pragma unroll
        for (int it = 0; it < 2; ++it) {
            int slot = it * 256 + tid;
            int row = slot >> 3, seg = slot & 7;
            size_t goff = rowbase + (size_t)(J * 64 + row) * 2048 + seg * 8;
            union { U4 v; u16 s[8]; } kv, vv;
            kv.v = *(const U4*)(Kb + goff);
            vv.v = *(const U4*)(Vb + goff);
            float wp = wpow[511 - (J * 64 + row)];
            #pragma unroll
            for (int e = 0; e < 8; ++e) {
                ktT[seg * 8 + e][row] = f2bf(bf2f(kv.s[e]) * wp);
                vtT[seg * 8 + e][row] = vv.s[e];
            }
        }
        __syncthreads();
        short8 a0 = lds8(&ktT[w * 16 + l16][quad * 8]);
        short8 a1 = lds8(&ktT[w * 16 + l16][32 + quad * 8]);
        #pragma unroll
        for (int nt = 0; nt < 4; ++nt) {
            short8 b0 = lds8(&vtT[nt * 16 + l16][quad * 8]);
            short8 b1 = lds8(&vtT[nt * 16 + l16][32 + quad * 8]);
            acc[nt] = __builtin_amdgcn_mfma_f32_16x16x32_bf16(a0, b0, acc[nt], 0, 0, 0);
            acc[nt] = __builtin_amdgcn_mfma_f32_16x16x32_bf16(a1, b1, acc[nt], 0, 0, 0);
        }
    }
    float* out = Sc + ((size_t)((b * 32 + h) * 8 + c) << 12);
    #pragma unroll
    for (int nt = 0; nt < 4; ++nt)
        #pragma unroll
        for (int r = 0; r < 4; ++r)
            out[(w * 16 + quad * 4 + r) * 64 + nt * 16 + l16] = acc[nt][r];
}

// ---------------------------------------------------------------------------
// WKV pass B: sequential chunk scan of states (fp32), emit bf16 transposed:
//   Sin[0] = st0;  Sin[c] = w1^512 * Sin[c-1] + Sc[c-1]
//   SinT[bh][c][s2][s1] = bf16(Sin[c][s1][s2])
// Grid 128 blocks (b*32+h), 256 threads; thread owns s2=tid&63, s1 in [s1b,s1b+16).
// ---------------------------------------------------------------------------
__global__ __launch_bounds__(256, 4) void wkv_scan(
    const float* __restrict__ Sc, const float* __restrict__ st0,
    const float* __restrict__ td, u16* __restrict__ SinT)
{
    const int blk = blockIdx.x;
    const int h = blk & 31;
    const int tid = threadIdx.x;
    const int s2 = tid & 63;
    const int s1b = (tid >> 6) * 16;
    const float wsT = expf(-512.f * expf(td[h]));

    float S[16];
    const float* sp = st0 + ((size_t)blk << 12);
    #pragma unroll
    for (int i = 0; i < 16; ++i) S[i] = sp[(s1b + i) * 64 + s2];

    const size_t base = ((size_t)blk * 8) << 12;
    for (int c = 0; c < 8; ++c) {
        u16* op = SinT + base + ((size_t)c << 12) + s2 * 64 + s1b;
        union { u16 s[16]; U4 v[2]; } ov;
        #pragma unroll
        for (int i = 0; i < 16; ++i) ov.s[i] = f2bf(S[i]);
        *(U4*)op = ov.v[0];
        *(U4*)(op + 8) = ov.v[1];
        if (c < 7) {
            const float* cp = Sc + base + ((size_t)c << 12);
            #pragma unroll
            for (int i = 0; i < 16; ++i)
                S[i] = wsT * S[i] + cp[(s1b + i) * 64 + s2];
        }
    }
}

// ---------------------------------------------------------------------------
// WKV pass C: per-(b,h,chunk) output
//   acc = (r @ Sin_c) * w1^i + tri_att(r,k) @ v ; groupnorm/silu epilogue.
// Grid 1024 blocks, 512 threads (8 waves, wave w owns rows [w*64, w*64+64)).
// ---------------------------------------------------------------------------
__global__ __launch_bounds__(512, 1) void wkv_out(
    const u16* __restrict__ Rb, const u16* __restrict__ Kb,
    const u16* __restrict__ Vb, const u16* __restrict__ Gb,
    const u16* __restrict__ SinT,
    const float* __restrict__ td, const float* __restrict__ tf,
    const float* __restrict__ gamma, const float* __restrict__ beta,
    u16* __restrict__ Xout)
{
    __shared__ u16 kt[64][72];     // k tile [t_local][s]
    __shared__ u16 vtT[64][72];    // v tile transposed [s][t_local]
    __shared__ u16 Pb[8][64][40];  // per-wave P scratch
    __shared__ float wpow[513];

    const int blk = blockIdx.x;
    const int c = blk & 7, h = (blk >> 3) & 31, b = blk >> 8;
    const int tid = threadIdx.x;
    const int w = tid >> 6, lane = tid & 63;
    const int quad = lane >> 4, l16 = lane & 15;

    const float E = expf(td[h]);
    const float u = tf[h];
    for (int p = tid; p <= 512; p += 512) wpow[p] = expf(-(float)p * E);

    const size_t rowbase = ((size_t)b * 4096 + c * 512) * 2048 + (size_t)h * 64;
    const f32x4 zero4 = {0.f, 0.f, 0.f, 0.f};
    __syncthreads();  // wpow ready

    // ---- r fragments for this wave's 64 rows ----
    short8 ar[4][2];
    #pragma unroll
    for (int mt = 0; mt < 4; ++mt)
        #pragma unroll
        for (int ks = 0; ks < 2; ++ks) {
            int t = w * 64 + mt * 16 + l16;
            const u16* p = Rb + rowbase + (size_t)t * 2048 + ks * 32 + quad * 8;
            union { U4 v; short8 s; } uu; uu.v = *(const U4*)p;
            ar[mt][ks] = uu.s;
        }

    // ---- phase 1: acc = (r @ Sin) * w1^i, B-frags straight from global ----
    const u16* sp = SinT + ((size_t)((b * 32 + h) * 8 + c) << 12);
    f32x4 acc[4][4];
    #pragma unroll
    for (int i = 0; i < 4; ++i)
        #pragma unroll
        for (int j = 0; j < 4; ++j) acc[i][j] = zero4;
    #pragma unroll
    for (int ks = 0; ks < 2; ++ks)
        #pragma unroll
        for (int nt = 0; nt < 4; ++nt) {
            union { U4 v; short8 s; } uu;
            uu.v = *(const U4*)(sp + (nt * 16 + l16) * 64 + ks * 32 + quad * 8);
            short8 bs = uu.s;
            #pragma unroll
            for (int mt = 0; mt < 4; ++mt)
                acc[mt][nt] = __builtin_amdgcn_mfma_f32_16x16x32_bf16(
                    ar[mt][ks], bs, acc[mt][nt], 0, 0, 0);
        }
    #pragma unroll
    for (int mt = 0; mt < 4; ++mt)
        #pragma unroll
        for (int r = 0; r < 4; ++r) {
            float f = wpow[w * 64 + mt * 16 + quad * 4 + r];
            #pragma unroll
            for (int nt = 0; nt < 4; ++nt) acc[mt][nt][r] *= f;
        }

    // ---- phase 2: triangular attention over J tiles ----
    for (int J = 0; J < 8; ++J) {
        __syncthreads();
        {   // stage kt, vtT
            int row = tid >> 3, seg = tid & 7;
            size_t goff = rowbase + (size_t)(J * 64 + row) * 2048 + seg * 8;
            union { U4 v; u16 s[8]; } kv, vv;
            kv.v = *(const U4*)(Kb + goff);
            vv.v = *(const U4*)(Vb + goff);
            *(U4*)&kt[row][seg * 8] = kv.v;
            #pragma unroll
            for (int e = 0; e < 8; ++e) vtT[seg * 8 + e][row] = vv.s[e];
        }
        __syncthreads();
        if (w >= J) {
            #pragma unroll
            for (int half = 0; half < 2; ++half) {
                #pragma unroll
                for (int jt2 = 0; jt2 < 2; ++jt2) {
                    int jt = half * 2 + jt2;
                    short8 bk0 = lds8(&kt[jt * 16 + l16][quad * 8]);
                    short8 bk1 = lds8(&kt[jt * 16 + l16][32 + quad * 8]);
                    #pragma unroll
                    for (int mt = 0; mt < 4; ++mt) {
                        f32x4 s4 = zero4;
                        s4 = __builtin_amdgcn_mfma_f32_16x16x32_bf16(ar[mt][0], bk0, s4, 0, 0, 0);
                        s4 = __builtin_amdgcn_mfma_f32_16x16x32_bf16(ar[mt][1], bk1, s4, 0, 0, 0);
                        int ibase = w * 64 + mt * 16 + quad * 4;
                        int j = J * 64 + jt * 16 + l16;
                        #pragma unroll
                        for (int r = 0; r < 4; ++r) {
                            int i = ibase + r;
                            float f = (j < i) ? wpow[i - j - 1] : ((j == i) ? u : 0.f);
                            Pb[w][mt * 16 + quad * 4 + r][jt2 * 16 + l16] = f2bf(s4[r] * f);
                        }
                    }
                }
                __builtin_amdgcn_wave_barrier();
                short8 ap[4];
                #pragma unroll
                for (int mt = 0; mt < 4; ++mt)
                    ap[mt] = lds8(&Pb[w][mt * 16 + l16][quad * 8]);
                #pragma unroll
                for (int nt = 0; nt < 4; ++nt) {
                    short8 bv = lds8(&vtT[nt * 16 + l16][half * 32 + quad * 8]);
                    #pragma unroll
                    for (int mt = 0; mt < 4; ++mt)
                        acc[mt][nt] = __builtin_amdgcn_mfma_f32_16x16x32_bf16(
                            ap[mt], bv, acc[mt][nt], 0, 0, 0);
                }
            }
        }
    }

    // ---- epilogue: groupnorm(out/8)*gamma+beta, * silu(g), write bf16 ----
    #pragma unroll
    for (int mt = 0; mt < 4; ++mt) {
        float rsum[4], rsq[4];
        #pragma unroll
        for (int r = 0; r < 4; ++r) {
            float s = 0.f, sq = 0.f;
            #pragma unroll
            for (int nt = 0; nt < 4; ++nt) {
                float v = acc[mt][nt][r];
                s += v; sq += v * v;
            }
            rsum[r] = s; rsq[r] = sq;
        }
        #pragma unroll
        for (int off = 1; off < 16; off <<= 1)
            #pragma unroll
            for (int r = 0; r < 4; ++r) {
                rsum[r] += __shfl_xor(rsum[r], off);
                rsq[r] += __shfl_xor(rsq[r], off);
            }
        #pragma unroll
        for (int r = 0; r < 4; ++r) {
            float mean = rsum[r] * (1.f / 512.f);
            float var = rsq[r] * (1.f / 4096.f) - mean * mean;
            float rstd = rsqrtf(var + 1e-5f);
            int tg = w * 64 + mt * 16 + quad * 4 + r;
            size_t obase = rowbase + (size_t)tg * 2048;
            #pragma unroll
            for (int nt = 0; nt < 4; ++nt) {
                int ch = nt * 16 + l16;
                float y = acc[mt][nt][r] * 0.125f;
                float xn = (y - mean) * rstd * gamma[h * 64 + ch] + beta[h * 64 + ch];
                float gl = bf2f(Gb[obase + ch]);
                float sg = gl / (1.f + expf(-gl));
                Xout[obase + ch] = f2bf(xn * sg);
            }
        }
    }
}

// ---------------------------------------------------------------------------
extern "C" void kernel_launch(void* const* d_in, const int* in_sizes, int n_in,
                              void* d_out, int out_size, void* d_ws, size_t ws_size,
                              hipStream_t stream)
{
    const float* x   = (const float*)d_in[0];
    const float* Wr  = (const float*)d_in[1];
    const float* Wk  = (const float*)d_in[2];
    const float* Wv  = (const float*)d_in[3];
    const float* Wg  = (const float*)d_in[4];
    const float* Wo  = (const float*)d_in[5];
    const float* gam = (const float*)d_in[6];
    const float* bet = (const float*)d_in[7];
    const float* tmk = (const float*)d_in[8];
    const float* tmv = (const float*)d_in[9];
    const float* tmr = (const float*)d_in[10];
    const float* tmg = (const float*)d_in[11];
    const float* td  = (const float*)d_in[12];
    const float* tf  = (const float*)d_in[13];
    const float* st0 = (const float*)d_in[14];
    float* out = (float*)d_out;

    char* ws = (char*)d_ws;
    const size_t WSZ = (size_t)2048 * 2048 * 2;   // 8 MiB per transposed bf16 weight
    const size_t ASZ = (size_t)16384 * 2048 * 2;  // 64 MiB per bf16 activation
    u16* WtR = (u16*)(ws + 0 * WSZ);
    u16* WtK = (u16*)(ws + 1 * WSZ);
    u16* WtV = (u16*)(ws + 2 * WSZ);
    u16* WtG = (u16*)(ws + 3 * WSZ);
    u16* WtO = (u16*)(ws + 4 * WSZ);
    char* act = ws + 5 * WSZ;
    u16* rb = (u16*)(act + 0 * ASZ);
    u16* kb = (u16*)(act + 1 * ASZ);
    u16* vb = (u16*)(act + 2 * ASZ);
    u16* gb = (u16*)(act + 3 * ASZ);
    u16* xo = gb;  // alias: wkv_out reads Gb[addr] strictly before writing Xout[addr]

    // d_out reuse (dead until the final GEMM):
    //  - during mix/proj phase: two mixed bf16 A buffers (2 x 64 MiB = 128 MiB)
    //  - during wkv phase: Sc fp32 (16.8 MiB) + SinT bf16 (8.4 MiB)
    u16* mixA = (u16*)d_out;
    u16* mixB = (u16*)d_out + (size_t)16384 * 2048;
    float* ScBuf = (float*)d_out;
    u16* SinT = (u16*)((char*)d_out + (size_t)1024 * 4096 * 4);

    transpose5<<<dim3(64, 64, 5), dim3(32, 8), 0, stream>>>(
        Wr, Wk, Wv, Wg, Wo, WtR, WtK, WtV, WtG, WtO);

    dim3 ggrid(128, 16), gblk(256);
    dim3 mgrid(16384), mblk(256);

    mix2_rows<<<mgrid, mblk, 0, stream>>>(x, tmr, tmk, mixA, mixB);
    gemm_bt<u16><<<ggrid, gblk, 0, stream>>>(mixA, WtR, rb, 16384, 2048, 2048);
    gemm_bt<u16><<<ggrid, gblk, 0, stream>>>(mixB, WtK, kb, 16384, 2048, 2048);
    mix2_rows<<<mgrid, mblk, 0, stream>>>(x, tmv, tmg, mixA, mixB);
    gemm_bt<u16><<<ggrid, gblk, 0, stream>>>(mixA, WtV, vb, 16384, 2048, 2048);
    gemm_bt<u16><<<ggrid, gblk, 0, stream>>>(mixB, WtG, gb, 16384, 2048, 2048);

    wkv_state<<<dim3(1024), dim3(256), 0, stream>>>(kb, vb, td, ScBuf);
    wkv_scan<<<dim3(128), dim3(256), 0, stream>>>(ScBuf, st0, td, SinT);
    wkv_out<<<dim3(1024), dim3(512), 0, stream>>>(
        rb, kb, vb, gb, SinT, td, tf, gam, bet, xo);

    gemm_bt<float><<<ggrid, gblk, 0, stream>>>(xo, WtO, out, 16384, 2048, 2048);
}

// Round 4
// 1505.446 us; speedup vs baseline: 1.4499x; 1.0680x over previous
//
#include <hip/hip_runtime.h>

typedef unsigned short u16;
typedef short short8 __attribute__((ext_vector_type(8)));
typedef float f32x4 __attribute__((ext_vector_type(4)));

struct __attribute__((aligned(8), may_alias)) U2 { unsigned int x, y; };
struct __attribute__((aligned(16), may_alias)) U4 { unsigned int x, y, z, w; };
struct __attribute__((aligned(16), may_alias)) F4 { float x, y, z, w; };

__device__ __forceinline__ float bf2f(u16 h) {
    union { unsigned int u; float f; } x; x.u = ((unsigned int)h) << 16; return x.f;
}
__device__ __forceinline__ u16 f2bf(float f) {
    union { float f; unsigned int u; } x; x.f = f;
    return (u16)((x.u + 0x7FFFu + ((x.u >> 16) & 1u)) >> 16);
}
__device__ __forceinline__ short8 lds8(const u16* p) {
    union { U2 q[2]; short8 s; } u;
    u.q[0] = *(const U2*)p;
    u.q[1] = *(const U2*)(p + 4);
    return u.s;
}
// async global->LDS, 16B per lane; LDS dest must be linear (base + lane*16)
__device__ __forceinline__ void gl_lds16(const u16* g, u16* l) {
    __builtin_amdgcn_global_load_lds(
        (const __attribute__((address_space(1))) void*)g,
        (__attribute__((address_space(3))) void*)l, 16, 0, 0);
}

// ---------------------------------------------------------------------------
// Transpose 5 fp32 weight matrices (2048x2048) into bf16: Wt[n][k] = bf16(W[k][n])
// ---------------------------------------------------------------------------
__global__ void transpose5(const float* __restrict__ s0, const float* __restrict__ s1,
                           const float* __restrict__ s2, const float* __restrict__ s3,
                           const float* __restrict__ s4,
                           u16* __restrict__ d0, u16* __restrict__ d1,
                           u16* __restrict__ d2, u16* __restrict__ d3,
                           u16* __restrict__ d4)
{
    const float* S; u16* D;
    switch (blockIdx.z) {
        case 0: S = s0; D = d0; break;
        case 1: S = s1; D = d1; break;
        case 2: S = s2; D = d2; break;
        case 3: S = s3; D = d3; break;
        default: S = s4; D = d4; break;
    }
    __shared__ float tile[32][33];
    int tx = threadIdx.x, ty = threadIdx.y;
    int bx = blockIdx.x * 32, by = blockIdx.y * 32;
    #pragma unroll
    for (int i = 0; i < 32; i += 8)
        tile[ty + i][tx] = S[(size_t)(by + ty + i) * 2048 + bx + tx];
    __syncthreads();
    #pragma unroll
    for (int i = 0; i < 32; i += 8)
        D[(size_t)(bx + ty + i) * 2048 + by + tx] = f2bf(tile[tx][ty + i]);
}

// ---------------------------------------------------------------------------
// Token-shift mix -> bf16, two params at once (halves x re-reads):
//   out[t][c] = bf16(xprev[c] + tmix[c]*(x[t][c]-xprev[c])), xprev=0 at t%4096==0
// ---------------------------------------------------------------------------
__global__ __launch_bounds__(256, 4) void mix2_rows(
    const float* __restrict__ x, const float* __restrict__ tmA,
    const float* __restrict__ tmB, u16* __restrict__ outA, u16* __restrict__ outB)
{
    const int t = blockIdx.x;
    const int c = threadIdx.x * 8;
    const float* xp = x + (size_t)t * 2048 + c;
    const bool first = (t & 4095) == 0;
    F4 a0 = *(const F4*)xp, a1 = *(const F4*)(xp + 4);
    F4 p0 = {0.f, 0.f, 0.f, 0.f}, p1 = {0.f, 0.f, 0.f, 0.f};
    if (!first) { p0 = *(const F4*)(xp - 2048); p1 = *(const F4*)(xp - 2048 + 4); }
    F4 ta0 = *(const F4*)(tmA + c), ta1 = *(const F4*)(tmA + c + 4);
    F4 tb0 = *(const F4*)(tmB + c), tb1 = *(const F4*)(tmB + c + 4);
    float xc[8] = {a0.x, a0.y, a0.z, a0.w, a1.x, a1.y, a1.z, a1.w};
    float xq[8] = {p0.x, p0.y, p0.z, p0.w, p1.x, p1.y, p1.z, p1.w};
    float ma[8] = {ta0.x, ta0.y, ta0.z, ta0.w, ta1.x, ta1.y, ta1.z, ta1.w};
    float mb[8] = {tb0.x, tb0.y, tb0.z, tb0.w, tb1.x, tb1.y, tb1.z, tb1.w};
    union { u16 s[8]; U4 v; } oa, ob;
    #pragma unroll
    for (int e = 0; e < 8; ++e) {
        float d = xc[e] - xq[e];
        oa.s[e] = f2bf(xq[e] + ma[e] * d);
        ob.s[e] = f2bf(xq[e] + mb[e] * d);
    }
    *(U4*)(outA + (size_t)t * 2048 + c) = oa.v;
    *(U4*)(outB + (size_t)t * 2048 + c) = ob.v;
}

// ---------------------------------------------------------------------------
// 2-phase double-buffered GEMM: C[M,N] = A_bf16[M,K] @ Bt_bf16[N,K]^T, fp32 acc.
// 128x128 tile, BK=32, global_load_lds staging of tile k+1 issued BEFORE the
// compute of tile k; ONE barrier per K-step (compiler drains vmcnt there).
// Grid: 2048 blocks 1D, XCD-swizzled: each XCD gets a contiguous 256-tile
// chunk = 16 M-panels x all 16 N-panels (B reused 16x inside one XCD L2).
// ---------------------------------------------------------------------------
__device__ __forceinline__ void storeC(u16* p, float v) { *p = f2bf(v); }
__device__ __forceinline__ void storeC(float* p, float v) { *p = v; }

template <typename CT>
__global__ __launch_bounds__(256, 1) void gemm_bt(
    const u16* __restrict__ A, const u16* __restrict__ Bt, CT* __restrict__ C,
    int M, int N, int K)
{
    __shared__ u16 As[2][128][32];
    __shared__ u16 Bs[2][128][32];
    const int tid = threadIdx.x;
    const int lane = tid & 63, wv = tid >> 6;
    const int quad = lane >> 4, l16 = lane & 15;
    const int wm = (wv >> 1) * 64, wn = (wv & 1) * 64;

    // XCD-aware swizzle (2048 blocks, 8 XCDs, bijective since 2048%8==0)
    const int wgid = blockIdx.x;
    const int tile = (wgid & 7) * 256 + (wgid >> 3);
    const int bm = (tile >> 4) * 128;    // 128 M-tiles
    const int bn = (tile & 15) * 128;    // 16 N-tiles

    const int sr = tid >> 2, ss = tid & 3;
    const u16* ga0 = A + (size_t)(bm + sr) * K + ss * 8;
    const u16* ga1 = A + (size_t)(bm + sr + 64) * K + ss * 8;
    const u16* gb0 = Bt + (size_t)(bn + sr) * K + ss * 8;
    const u16* gb1 = Bt + (size_t)(bn + sr + 64) * K + ss * 8;

    f32x4 acc[4][4];
    const f32x4 zero4 = {0.f, 0.f, 0.f, 0.f};
    #pragma unroll
    for (int i = 0; i < 4; ++i)
        #pragma unroll
        for (int j = 0; j < 4; ++j) acc[i][j] = zero4;

    // prologue: stage tile 0 into buf 0
    gl_lds16(ga0, &As[0][sr][ss * 8]);
    gl_lds16(ga1, &As[0][sr + 64][ss * 8]);
    gl_lds16(gb0, &Bs[0][sr][ss * 8]);
    gl_lds16(gb1, &Bs[0][sr + 64][ss * 8]);
    __syncthreads();

    int cur = 0;
    for (int k0 = 0; k0 < K; k0 += 32) {
        if (k0 + 32 < K) {          // issue next tile first (latency hides under MFMA)
            int nxt = cur ^ 1;
            gl_lds16(ga0 + k0 + 32, &As[nxt][sr][ss * 8]);
            gl_lds16(ga1 + k0 + 32, &As[nxt][sr + 64][ss * 8]);
            gl_lds16(gb0 + k0 + 32, &Bs[nxt][sr][ss * 8]);
            gl_lds16(gb1 + k0 + 32, &Bs[nxt][sr + 64][ss * 8]);
        }
        short8 af[4], bfv[4];
        #pragma unroll
        for (int mt = 0; mt < 4; ++mt) af[mt] = lds8(&As[cur][wm + mt * 16 + l16][quad * 8]);
        #pragma unroll
        for (int nt = 0; nt < 4; ++nt) bfv[nt] = lds8(&Bs[cur][wn + nt * 16 + l16][quad * 8]);
        #pragma unroll
        for (int mt = 0; mt < 4; ++mt)
            #pragma unroll
            for (int nt = 0; nt < 4; ++nt)
                acc[mt][nt] = __builtin_amdgcn_mfma_f32_16x16x32_bf16(
                    af[mt], bfv[nt], acc[mt][nt], 0, 0, 0);
        __syncthreads();            // drains vmcnt (next tile resident) + lgkm
        cur ^= 1;
    }
    #pragma unroll
    for (int mt = 0; mt < 4; ++mt)
        #pragma unroll
        for (int nt = 0; nt < 4; ++nt)
            #pragma unroll
            for (int r = 0; r < 4; ++r) {
                int row = bm + wm + mt * 16 + quad * 4 + r;
                int col = bn + wn + nt * 16 + l16;
                storeC(&C[(size_t)row * N + col], acc[mt][nt][r]);
            }
}

// ---------------------------------------------------------------------------
// WKV pass A: per-(b,h,chunk) state contribution
//   Sc[s1][s2] = sum_t k[t][s1] * w1^(511-t) * v[t][s2]   (t chunk-local)
// ---------------------------------------------------------------------------
__global__ __launch_bounds__(256, 2) void wkv_state(
    const u16* __restrict__ Kb, const u16* __restrict__ Vb,
    const float* __restrict__ td, float* __restrict__ Sc)
{
    __shared__ u16 ktT[64][72];   // [s][t_local]  pre-scaled by w1^(511-t)
    __shared__ u16 vtT[64][72];   // [s][t_local]
    __shared__ float wpow[512];

    const int blk = blockIdx.x;
    const int c = blk & 7, h = (blk >> 3) & 31, b = blk >> 8;
    const int tid = threadIdx.x;
    const int w = tid >> 6, lane = tid & 63;
    const int quad = lane >> 4, l16 = lane & 15;

    const float E = expf(td[h]);
    for (int p = tid; p < 512; p += 256) wpow[p] = expf(-(float)p * E);

    const size_t rowbase = ((size_t)b * 4096 + c * 512) * 2048 + (size_t)h * 64;
    const f32x4 zero4 = {0.f, 0.f, 0.f, 0.f};
    f32x4 acc[4];
    #pragma unroll
    for (int nt = 0; nt < 4; ++nt) acc[nt] = zero4;
    __syncthreads();  // wpow ready

    for (int J = 0; J < 8; ++J) {
        __syncthreads();
        #pragma unroll
        for (int it = 0; it < 2; ++it) {
            int slot = it * 256 + tid;
            int row = slot >> 3, seg = slot & 7;
            size_t goff = rowbase + (size_t)(J * 64 + row) * 2048 + seg * 8;
            union { U4 v; u16 s[8]; } kv, vv;
            kv.v = *(const U4*)(Kb + goff);
            vv.v = *(const U4*)(Vb + goff);
            float wp = wpow[511 - (J * 64 + row)];
            #pragma unroll
            for (int e = 0; e < 8; ++e) {
                ktT[seg * 8 + e][row] = f2bf(bf2f(kv.s[e]) * wp);
                vtT[seg * 8 + e][row] = vv.s[e];
            }
        }
        __syncthreads();
        short8 a0 = lds8(&ktT[w * 16 + l16][quad * 8]);
        short8 a1 = lds8(&ktT[w * 16 + l16][32 + quad * 8]);
        #pragma unroll
        for (int nt = 0; nt < 4; ++nt) {
            short8 b0 = lds8(&vtT[nt * 16 + l16][quad * 8]);
            short8 b1 = lds8(&vtT[nt * 16 + l16][32 + quad * 8]);
            acc[nt] = __builtin_amdgcn_mfma_f32_16x16x32_bf16(a0, b0, acc[nt], 0, 0, 0);
            acc[nt] = __builtin_amdgcn_mfma_f32_16x16x32_bf16(a1, b1, acc[nt], 0, 0, 0);
        }
    }
    float* out = Sc + ((size_t)((b * 32 + h) * 8 + c) << 12);
    #pragma unroll
    for (int nt = 0; nt < 4; ++nt)
        #pragma unroll
        for (int r = 0; r < 4; ++r)
            out[(w * 16 + quad * 4 + r) * 64 + nt * 16 + l16] = acc[nt][r];
}

// ---------------------------------------------------------------------------
// WKV pass B: sequential chunk scan of states (fp32), emit bf16 transposed.
// ---------------------------------------------------------------------------
__global__ __launch_bounds__(256, 4) void wkv_scan(
    const float* __restrict__ Sc, const float* __restrict__ st0,
    const float* __restrict__ td, u16* __restrict__ SinT)
{
    const int blk = blockIdx.x;
    const int h = blk & 31;
    const int tid = threadIdx.x;
    const int s2 = tid & 63;
    const int s1b = (tid >> 6) * 16;
    const float wsT = expf(-512.f * expf(td[h]));

    float S[16];
    const float* sp = st0 + ((size_t)blk << 12);
    #pragma unroll
    for (int i = 0; i < 16; ++i) S[i] = sp[(s1b + i) * 64 + s2];

    const size_t base = ((size_t)blk * 8) << 12;
    for (int c = 0; c < 8; ++c) {
        u16* op = SinT + base + ((size_t)c << 12) + s2 * 64 + s1b;
        union { u16 s[16]; U4 v[2]; } ov;
        #pragma unroll
        for (int i = 0; i < 16; ++i) ov.s[i] = f2bf(S[i]);
        *(U4*)op = ov.v[0];
        *(U4*)(op + 8) = ov.v[1];
        if (c < 7) {
            const float* cp = Sc + base + ((size_t)c << 12);
            #pragma unroll
            for (int i = 0; i < 16; ++i)
                S[i] = wsT * S[i] + cp[(s1b + i) * 64 + s2];
        }
    }
}

// ---------------------------------------------------------------------------
// WKV pass C: per-(b,h,chunk) output.
// P-mask: for strictly-lower tiles (J < w) the decay factors as
//   w1^(i-j-1) = wpow[a]*wpow[b], a = row-in-wave, b = tile/lane offset,
// removing the per-element wpow gather (bank conflicts) and the mask branch.
// Diagonal tiles (J == w) keep the per-element masked path.
// ---------------------------------------------------------------------------
__global__ __launch_bounds__(512, 1) void wkv_out(
    const u16* __restrict__ Rb, const u16* __restrict__ Kb,
    const u16* __restrict__ Vb, const u16* __restrict__ Gb,
    const u16* __restrict__ SinT,
    const float* __restrict__ td, const float* __restrict__ tf,
    const float* __restrict__ gamma, const float* __restrict__ beta,
    u16* __restrict__ Xout)
{
    __shared__ u16 kt[64][72];     // k tile [t_local][s]
    __shared__ u16 vtT[64][72];    // v tile transposed [s][t_local]
    __shared__ u16 Pb[8][64][40];  // per-wave P scratch
    __shared__ float wpow[513];

    const int blk = blockIdx.x;
    const int c = blk & 7, h = (blk >> 3) & 31, b = blk >> 8;
    const int tid = threadIdx.x;
    const int w = tid >> 6, lane = tid & 63;
    const int quad = lane >> 4, l16 = lane & 15;

    const float E = expf(td[h]);
    const float u = tf[h];
    for (int p = tid; p <= 512; p += 512) wpow[p] = expf(-(float)p * E);

    const size_t rowbase = ((size_t)b * 4096 + c * 512) * 2048 + (size_t)h * 64;
    const f32x4 zero4 = {0.f, 0.f, 0.f, 0.f};
    __syncthreads();  // wpow ready

    // ---- r fragments for this wave's 64 rows ----
    short8 ar[4][2];
    #pragma unroll
    for (int mt = 0; mt < 4; ++mt)
        #pragma unroll
        for (int ks = 0; ks < 2; ++ks) {
            int t = w * 64 + mt * 16 + l16;
            const u16* p = Rb + rowbase + (size_t)t * 2048 + ks * 32 + quad * 8;
            union { U4 v; short8 s; } uu; uu.v = *(const U4*)p;
            ar[mt][ks] = uu.s;
        }

    // ---- phase 1: acc = (r @ Sin) * w1^i, B-frags straight from global ----
    const u16* sp = SinT + ((size_t)((b * 32 + h) * 8 + c) << 12);
    f32x4 acc[4][4];
    #pragma unroll
    for (int i = 0; i < 4; ++i)
        #pragma unroll
        for (int j = 0; j < 4; ++j) acc[i][j] = zero4;
    #pragma unroll
    for (int ks = 0; ks < 2; ++ks)
        #pragma unroll
        for (int nt = 0; nt < 4; ++nt) {
            union { U4 v; short8 s; } uu;
            uu.v = *(const U4*)(sp + (nt * 16 + l16) * 64 + ks * 32 + quad * 8);
            short8 bs = uu.s;
            #pragma unroll
            for (int mt = 0; mt < 4; ++mt)
                acc[mt][nt] = __builtin_amdgcn_mfma_f32_16x16x32_bf16(
                    ar[mt][ks], bs, acc[mt][nt], 0, 0, 0);
        }
    #pragma unroll
    for (int mt = 0; mt < 4; ++mt)
        #pragma unroll
        for (int r = 0; r < 4; ++r) {
            float f = wpow[w * 64 + mt * 16 + quad * 4 + r];
            #pragma unroll
            for (int nt = 0; nt < 4; ++nt) acc[mt][nt][r] *= f;
        }

    // per-(mt,r) decay factors for the factored fast path
    float wAr[4][4];
    #pragma unroll
    for (int mt = 0; mt < 4; ++mt)
        #pragma unroll
        for (int r = 0; r < 4; ++r)
            wAr[mt][r] = wpow[mt * 16 + quad * 4 + r];

    // ---- phase 2: triangular attention over J tiles ----
    for (int J = 0; J < 8; ++J) {
        __syncthreads();
        {   // stage kt, vtT
            int row = tid >> 3, seg = tid & 7;
            size_t goff = rowbase + (size_t)(J * 64 + row) * 2048 + seg * 8;
            union { U4 v; u16 s[8]; } kv, vv;
            kv.v = *(const U4*)(Kb + goff);
            vv.v = *(const U4*)(Vb + goff);
            *(U4*)&kt[row][seg * 8] = kv.v;
            #pragma unroll
            for (int e = 0; e < 8; ++e) vtT[seg * 8 + e][row] = vv.s[e];
        }
        __syncthreads();
        if (w >= J) {
            #pragma unroll
            for (int half = 0; half < 2; ++half) {
                #pragma unroll
                for (int jt2 = 0; jt2 < 2; ++jt2) {
                    int jt = half * 2 + jt2;
                    short8 bk0 = lds8(&kt[jt * 16 + l16][quad * 8]);
                    short8 bk1 = lds8(&kt[jt * 16 + l16][32 + quad * 8]);
                    if (w > J) {
                        // strictly-lower tile: branchless factored decay
                        float wB = wpow[((w - J) << 6) - jt * 16 - l16 - 1];
                        #pragma unroll
                        for (int mt = 0; mt < 4; ++mt) {
                            f32x4 s4 = zero4;
                            s4 = __builtin_amdgcn_mfma_f32_16x16x32_bf16(ar[mt][0], bk0, s4, 0, 0, 0);
                            s4 = __builtin_amdgcn_mfma_f32_16x16x32_bf16(ar[mt][1], bk1, s4, 0, 0, 0);
                            #pragma unroll
                            for (int r = 0; r < 4; ++r)
                                Pb[w][mt * 16 + quad * 4 + r][jt2 * 16 + l16] =
                                    f2bf(s4[r] * (wAr[mt][r] * wB));
                        }
                    } else {
                        // diagonal tile: per-element mask
                        #pragma unroll
                        for (int mt = 0; mt < 4; ++mt) {
                            f32x4 s4 = zero4;
                            s4 = __builtin_amdgcn_mfma_f32_16x16x32_bf16(ar[mt][0], bk0, s4, 0, 0, 0);
                            s4 = __builtin_amdgcn_mfma_f32_16x16x32_bf16(ar[mt][1], bk1, s4, 0, 0, 0);
                            int ibase = w * 64 + mt * 16 + quad * 4;
                            int j = J * 64 + jt * 16 + l16;
                            #pragma unroll
                            for (int r = 0; r < 4; ++r) {
                                int i = ibase + r;
                                float f = (j < i) ? wpow[i - j - 1] : ((j == i) ? u : 0.f);
                                Pb[w][mt * 16 + quad * 4 + r][jt2 * 16 + l16] = f2bf(s4[r] * f);
                            }
                        }
                    }
                }
                __builtin_amdgcn_wave_barrier();
                short8 ap[4];
                #pragma unroll
                for (int mt = 0; mt < 4; ++mt)
                    ap[mt] = lds8(&Pb[w][mt * 16 + l16][quad * 8]);
                #pragma unroll
                for (int nt = 0; nt < 4; ++nt) {
                    short8 bv = lds8(&vtT[nt * 16 + l16][half * 32 + quad * 8]);
                    #pragma unroll
                    for (int mt = 0; mt < 4; ++mt)
                        acc[mt][nt] = __builtin_amdgcn_mfma_f32_16x16x32_bf16(
                            ap[mt], bv, acc[mt][nt], 0, 0, 0);
                }
            }
        }
    }

    // ---- epilogue: groupnorm(out/8)*gamma+beta, * silu(g), write bf16 ----
    #pragma unroll
    for (int mt = 0; mt < 4; ++mt) {
        float rsum[4], rsq[4];
        #pragma unroll
        for (int r = 0; r < 4; ++r) {
            float s = 0.f, sq = 0.f;
            #pragma unroll
            for (int nt = 0; nt < 4; ++nt) {
                float v = acc[mt][nt][r];
                s += v; sq += v * v;
            }
            rsum[r] = s; rsq[r] = sq;
        }
        #pragma unroll
        for (int off = 1; off < 16; off <<= 1)
            #pragma unroll
            for (int r = 0; r < 4; ++r) {
                rsum[r] += __shfl_xor(rsum[r], off);
                rsq[r] += __shfl_xor(rsq[r], off);
            }
        #pragma unroll
        for (int r = 0; r < 4; ++r) {
            float mean = rsum[r] * (1.f / 512.f);
            float var = rsq[r] * (1.f / 4096.f) - mean * mean;
            float rstd = rsqrtf(var + 1e-5f);
            int tg = w * 64 + mt * 16 + quad * 4 + r;
            size_t obase = rowbase + (size_t)tg * 2048;
            #pragma unroll
            for (int nt = 0; nt < 4; ++nt) {
                int ch = nt * 16 + l16;
                float y = acc[mt][nt][r] * 0.125f;
                float xn = (y - mean) * rstd * gamma[h * 64 + ch] + beta[h * 64 + ch];
                float gl = bf2f(Gb[obase + ch]);
                float sg = gl / (1.f + expf(-gl));
                Xout[obase + ch] = f2bf(xn * sg);
            }
        }
    }
}

// ---------------------------------------------------------------------------
extern "C" void kernel_launch(void* const* d_in, const int* in_sizes, int n_in,
                              void* d_out, int out_size, void* d_ws, size_t ws_size,
                              hipStream_t stream)
{
    const float* x   = (const float*)d_in[0];
    const float* Wr  = (const float*)d_in[1];
    const float* Wk  = (const float*)d_in[2];
    const float* Wv  = (const float*)d_in[3];
    const float* Wg  = (const float*)d_in[4];
    const float* Wo  = (const float*)d_in[5];
    const float* gam = (const float*)d_in[6];
    const float* bet = (const float*)d_in[7];
    const float* tmk = (const float*)d_in[8];
    const float* tmv = (const float*)d_in[9];
    const float* tmr = (const float*)d_in[10];
    const float* tmg = (const float*)d_in[11];
    const float* td  = (const float*)d_in[12];
    const float* tf  = (const float*)d_in[13];
    const float* st0 = (const float*)d_in[14];
    float* out = (float*)d_out;

    char* ws = (char*)d_ws;
    const size_t WSZ = (size_t)2048 * 2048 * 2;   // 8 MiB per transposed bf16 weight
    const size_t ASZ = (size_t)16384 * 2048 * 2;  // 64 MiB per bf16 activation
    u16* WtR = (u16*)(ws + 0 * WSZ);
    u16* WtK = (u16*)(ws + 1 * WSZ);
    u16* WtV = (u16*)(ws + 2 * WSZ);
    u16* WtG = (u16*)(ws + 3 * WSZ);
    u16* WtO = (u16*)(ws + 4 * WSZ);
    char* act = ws + 5 * WSZ;
    u16* rb = (u16*)(act + 0 * ASZ);
    u16* kb = (u16*)(act + 1 * ASZ);
    u16* vb = (u16*)(act + 2 * ASZ);
    u16* gb = (u16*)(act + 3 * ASZ);
    u16* xo = gb;  // alias: wkv_out reads Gb[addr] strictly before writing Xout[addr]

    // d_out reuse (dead until the final GEMM)
    u16* mixA = (u16*)d_out;
    u16* mixB = (u16*)d_out + (size_t)16384 * 2048;
    float* ScBuf = (float*)d_out;
    u16* SinT = (u16*)((char*)d_out + (size_t)1024 * 4096 * 4);

    transpose5<<<dim3(64, 64, 5), dim3(32, 8), 0, stream>>>(
        Wr, Wk, Wv, Wg, Wo, WtR, WtK, WtV, WtG, WtO);

    dim3 ggrid(2048), gblk(256);
    dim3 mgrid(16384), mblk(256);

    mix2_rows<<<mgrid, mblk, 0, stream>>>(x, tmr, tmk, mixA, mixB);
    gemm_bt<u16><<<ggrid, gblk, 0, stream>>>(mixA, WtR, rb, 16384, 2048, 2048);
    gemm_bt<u16><<<ggrid, gblk, 0, stream>>>(mixB, WtK, kb, 16384, 2048, 2048);
    mix2_rows<<<mgrid, mblk, 0, stream>>>(x, tmv, tmg, mixA, mixB);
    gemm_bt<u16><<<ggrid, gblk, 0, stream>>>(mixA, WtV, vb, 16384, 2048, 2048);
    gemm_bt<u16><<<ggrid, gblk, 0, stream>>>(mixB, WtG, gb, 16384, 2048, 2048);

    wkv_state<<<dim3(1024), dim3(256), 0, stream>>>(kb, vb, td, ScBuf);
    wkv_scan<<<dim3(128), dim3(256), 0, stream>>>(ScBuf, st0, td, SinT);
    wkv_out<<<dim3(1024), dim3(512), 0, stream>>>(
        rb, kb, vb, gb, SinT, td, tf, gam, bet, xo);

    gemm_bt<float><<<ggrid, gblk, 0, stream>>>(xo, WtO, out, 16384, 2048, 2048);
}